// Round 19
// baseline (132.550 us; speedup 1.0000x reference)
//
#include <hip/hip_runtime.h>
#include <hip/hip_bf16.h>
#include <math.h>

// bucket = 64 consecutive dst nodes. key packs (dlow<<17 | src), valid for n < 131072.
#define BSHIFT 6
#define BNODES 64
#define MAXB 1024   // max buckets supported by single-block scan (n <= 65536)
#define SORTCAP 4096

// ---------------- inline dtype detection: int64 vs int32 edge_index ----------------
__device__ __forceinline__ bool detect_f64(const void* edges, long long nn) {
    const long long* e64 = (const long long*)edges;
    bool ok = true;
#pragma unroll
    for (int i = 0; i < 8; ++i) {
        long long v = e64[i];
        ok = ok && (v >= 0 && v < nn);
    }
    return ok;
}

__device__ __forceinline__ float bf16lo(unsigned int u) {
    return __uint_as_float(u << 16);
}
__device__ __forceinline__ float bf16hi(unsigned int u) {
    return __uint_as_float(u & 0xFFFF0000u);
}
__device__ __forceinline__ float bf16dec(unsigned short u) {
    return __uint_as_float(((unsigned int)u) << 16);
}
__device__ __forceinline__ unsigned short bf16enc(float f) {
    __hip_bfloat16 h = __float2bfloat16(f);
    return *reinterpret_cast<unsigned short*>(&h);
}

// ---- (A) FAT kernel: blocks [0,nblk) = per-slice histogram; rest = GEMM1 ----
// gemm1 writes h1 as TWO [n][32] bf16 planes (each 3.2MB -> per-XCD-L2-resident).
__global__ __launch_bounds__(256) void k_hist_gemm1(const void* edges, long long nn,
                                                    long long E, long long epb,
                                                    int nbuckets, int nblk, int* partial,
                                                    const float* __restrict__ x,
                                                    const float* __restrict__ W1,
                                                    unsigned short* __restrict__ h1lo,
                                                    unsigned short* __restrict__ h1hi) {
    __shared__ __align__(16) char smem[20480];   // hist: 4KB cnt | gemm1: 16KB Ws + 4KB xs
    int t = threadIdx.x;
    if (blockIdx.x < (unsigned int)nblk) {
        int* cnt = (int*)smem;
        int i = blockIdx.x;
        for (int b = t; b < nbuckets; b += 256) cnt[b] = 0;
        __syncthreads();
        bool f64 = detect_f64(edges, nn);
        long long e0 = (long long)i * epb;
        long long e1 = e0 + epb; if (e1 > E) e1 = E;
        for (long long e = e0 + t; e < e1; e += 256) {
            int d = f64 ? (int)((const long long*)edges)[E + e] : ((const int*)edges)[E + e];
            atomicAdd(&cnt[d >> BSHIFT], 1);
        }
        __syncthreads();
        for (int b = t; b < nbuckets; b += 256) partial[b * nblk + i] = cnt[b];
    } else {
        float (*Ws)[64] = (float(*)[64])smem;
        float (*xs)[64] = (float(*)[64])(smem + 64 * 64 * 4);
        for (int i = t; i < 64 * 64; i += 256) Ws[i >> 6][i & 63] = W1[i];
        long long row0 = (long long)(blockIdx.x - nblk) * 16;
        ((float4*)xs)[t] = ((const float4*)(x + row0 * 64))[t];
        __syncthreads();
        int r = t >> 4, c0 = (t & 15) * 4;
        float4 acc = {0.f, 0.f, 0.f, 0.f};
#pragma unroll
        for (int k = 0; k < 64; ++k) {
            float xv = xs[r][k];
            float4 wv = *((const float4*)&Ws[k][c0]);
            acc.x += xv * wv.x; acc.y += xv * wv.y;
            acc.z += xv * wv.z; acc.w += xv * wv.w;
        }
        ushort4 pk;
        pk.x = bf16enc(acc.x);
        pk.y = bf16enc(acc.y);
        pk.z = bf16enc(acc.z);
        pk.w = bf16enc(acc.w);
        unsigned short* dst = (c0 < 32) ? (h1lo + (row0 + r) * 32 + c0)
                                        : (h1hi + (row0 + r) * 32 + (c0 - 32));
        *((ushort4*)dst) = pk;
    }
}

// ---- (B) per-bucket exclusive scan over blocks; emits bucket totals ----
__global__ __launch_bounds__(256) void k_scanB(int* partial, int nblk, int* totals) {
    __shared__ int tmp[256];
    int b = blockIdx.x, t = threadIdx.x;
    int v = (t < nblk) ? partial[b * nblk + t] : 0;
    tmp[t] = v;
    __syncthreads();
    for (int off = 1; off < 256; off <<= 1) {
        int a = (t >= off) ? tmp[t - off] : 0;
        __syncthreads();
        tmp[t] += a;
        __syncthreads();
    }
    if (t < nblk) partial[b * nblk + t] = tmp[t] - v;  // exclusive over blocks
    if (t == 255) totals[b] = tmp[255];
}

// ---- (C) bucket-level exclusive scan: base = exclusive(totals) ----
__global__ __launch_bounds__(1024) void k_scan(const int* __restrict__ totals, int nbuckets,
                                               int* base) {
    __shared__ int tmp[MAXB];
    int t = threadIdx.x;
    int v = (t < nbuckets) ? totals[t] : 0;
    tmp[t] = v;
    __syncthreads();
    for (int off = 1; off < MAXB; off <<= 1) {
        int a = (t >= off) ? tmp[t - off] : 0;
        __syncthreads();
        tmp[t] += a;
        __syncthreads();
    }
    if (t < nbuckets) base[t] = tmp[t] - v;
}

// ---- (D) place keys: LDS cursors seeded from base+partial; no global atomics ----
__global__ __launch_bounds__(512) void k_place(const void* edges, long long nn,
                                               long long E, long long epb,
                                               int nbuckets, int nblk,
                                               const int* __restrict__ base,
                                               const int* __restrict__ partial,
                                               unsigned int* keys) {
    __shared__ int cur[MAXB];
    int t = threadIdx.x;
    int i = blockIdx.x;
    for (int b = t; b < nbuckets; b += 512) cur[b] = base[b] + partial[b * nblk + i];
    __syncthreads();
    bool f64 = detect_f64(edges, nn);
    long long e0 = (long long)i * epb;
    long long e1 = e0 + epb; if (e1 > E) e1 = E;
    for (long long e = e0 + t; e < e1; e += 512) {
        int s, d;
        if (f64) {
            const long long* ee = (const long long*)edges;
            s = (int)ee[e]; d = (int)ee[E + e];
        } else {
            const int* ee = (const int*)edges;
            s = ee[e]; d = ee[E + e];
        }
        int pos = atomicAdd(&cur[d >> BSHIFT], 1);
        keys[pos] = (unsigned int)s | ((unsigned int)(d & (BNODES - 1)) << 17);
    }
}

// -------- per-bucket LDS counting sort -> node-exact CSR; fuses deg/dinv --------
__global__ __launch_bounds__(256) void k_sortdeg(unsigned int* keys,
                                                 const int* __restrict__ base,
                                                 const int* __restrict__ totals,
                                                 int* rowstart, int* counts,
                                                 float* dinv, int n,
                                                 unsigned int* scratch) {
    __shared__ unsigned int kbuf[SORTCAP];
    __shared__ int hist[BNODES];
    __shared__ int cur[BNODES];
    int t = threadIdx.x;
    int bk = blockIdx.x;
    int st = base[bk], c = totals[bk];
    if (t < BNODES) hist[t] = 0;
    __syncthreads();
    bool fits = (c <= SORTCAP);
    if (fits) {
        for (int i = t; i < c; i += 256) {
            unsigned int k = keys[st + i];
            kbuf[i] = k;
            atomicAdd(&hist[k >> 17], 1);
        }
    } else {  // statistically never for random edges; correct fallback via global scratch
        for (int i = t; i < c; i += 256) {
            unsigned int k = keys[st + i];
            scratch[st + i] = k;
            atomicAdd(&hist[k >> 17], 1);
        }
    }
    __syncthreads();
    if (t < 64) {  // wave 0: scan 64 counters
        int v = hist[t];
        int incl = v;
        for (int o = 1; o < 64; o <<= 1) {
            int other = __shfl_up(incl, o, 64);
            if (t >= o) incl += other;
        }
        int ex = incl - v;
        cur[t] = ex;
        int node = bk * BNODES + t;
        if (node < n) {
            rowstart[node] = st + ex;
            counts[node] = v;
            dinv[node] = rsqrtf((float)v + 1.0f);
        }
    }
    __syncthreads();
    if (fits) {
        for (int i = t; i < c; i += 256) {
            unsigned int k = kbuf[i];
            int pos = atomicAdd(&cur[k >> 17], 1);
            keys[st + pos] = k & 0x1FFFFu;
        }
    } else {
        for (int i = t; i < c; i += 256) {
            unsigned int k = scratch[st + i];
            int pos = atomicAdd(&cur[k >> 17], 1);
            keys[st + pos] = k & 0x1FFFFu;
        }
    }
}

// ------- Pass A: aggregate feats 0-31 from L2-resident 3.2MB plane -------
// 16 lanes x uint (4B) cover a 64B row; quarter-waves process edges k+0..k+3.
__global__ __launch_bounds__(256) void k_agg64A(const int* __restrict__ rowstart,
                                                const int* __restrict__ counts,
                                                const unsigned int* __restrict__ srcs,
                                                const unsigned int* __restrict__ tbl,
                                                const float* __restrict__ dinv,
                                                const float* __restrict__ b,
                                                unsigned int* __restrict__ outA, int n) {
    int d = (blockIdx.x * 256 + threadIdx.x) >> 6;
    if (d >= n) return;
    int lane = threadIdx.x & 63;
    unsigned int q = lane >> 4;
    unsigned int fl = lane & 15;     // feature pair (2fl, 2fl+1) of 32
    float di = dinv[d];
    float a0 = 0.f, a1 = 0.f;
    if (q == 0) {
        unsigned int u = tbl[(unsigned int)d * 16u + fl];
        a0 = di * bf16lo(u); a1 = di * bf16hi(u);
    }
    int start = rowstart[d];
    int cnt = counts[d];
    int k = 0;
    for (; k + 16 <= cnt; k += 16) {
        unsigned int s0 = srcs[start + k + q];
        unsigned int s1 = srcs[start + k + 4 + q];
        unsigned int s2 = srcs[start + k + 8 + q];
        unsigned int s3 = srcs[start + k + 12 + q];
        float dv0 = dinv[s0], dv1 = dinv[s1], dv2 = dinv[s2], dv3 = dinv[s3];
        unsigned int u0 = tbl[s0 * 16u + fl];
        unsigned int u1 = tbl[s1 * 16u + fl];
        unsigned int u2 = tbl[s2 * 16u + fl];
        unsigned int u3 = tbl[s3 * 16u + fl];
        a0 = fmaf(dv0, bf16lo(u0), a0); a1 = fmaf(dv0, bf16hi(u0), a1);
        a0 = fmaf(dv1, bf16lo(u1), a0); a1 = fmaf(dv1, bf16hi(u1), a1);
        a0 = fmaf(dv2, bf16lo(u2), a0); a1 = fmaf(dv2, bf16hi(u2), a1);
        a0 = fmaf(dv3, bf16lo(u3), a0); a1 = fmaf(dv3, bf16hi(u3), a1);
    }
    for (; k + 8 <= cnt; k += 8) {
        unsigned int s0 = srcs[start + k + q];
        unsigned int s1 = srcs[start + k + 4 + q];
        float dv0 = dinv[s0], dv1 = dinv[s1];
        unsigned int u0 = tbl[s0 * 16u + fl];
        unsigned int u1 = tbl[s1 * 16u + fl];
        a0 = fmaf(dv0, bf16lo(u0), a0); a1 = fmaf(dv0, bf16hi(u0), a1);
        a0 = fmaf(dv1, bf16lo(u1), a0); a1 = fmaf(dv1, bf16hi(u1), a1);
    }
    for (; k < cnt; k += 4) {
        int idx = k + (int)q;
        if (idx < cnt) {
            unsigned int s0 = srcs[start + idx];
            float dv0 = dinv[s0];
            unsigned int u0 = tbl[s0 * 16u + fl];
            a0 = fmaf(dv0, bf16lo(u0), a0); a1 = fmaf(dv0, bf16hi(u0), a1);
        }
    }
    a0 += __shfl_xor(a0, 16); a0 += __shfl_xor(a0, 32);
    a1 += __shfl_xor(a1, 16); a1 += __shfl_xor(a1, 32);
    if (q == 0) {
        float2 bb = ((const float2*)b)[fl];
        float o0 = fmaxf(di * a0 + bb.x, 0.f);
        float o1 = fmaxf(di * a1 + bb.y, 0.f);
        outA[(unsigned int)d * 16u + fl] =
            (unsigned int)bf16enc(o0) | ((unsigned int)bf16enc(o1) << 16);
    }
}

// ------- Pass B: aggregate feats 32-63 + FUSED GEMM2 (reads pass A output) -------
__global__ __launch_bounds__(256) void k_agg64B(const int* __restrict__ rowstart,
                                                const int* __restrict__ counts,
                                                const unsigned int* __restrict__ srcs,
                                                const unsigned int* __restrict__ tbl,
                                                const float* __restrict__ dinv,
                                                const float* __restrict__ b,
                                                const float* __restrict__ W2,
                                                const unsigned int* __restrict__ outA,
                                                unsigned short* __restrict__ h2b, int n) {
    __shared__ float W2s[64 * 17];
    int t = threadIdx.x;
    for (int i = t; i < 64 * 16; i += 256) W2s[(i >> 4) * 17 + (i & 15)] = W2[i];
    __syncthreads();  // before any divergence

    int d = (blockIdx.x * 256 + t) >> 6;
    if (d >= n) return;
    int lane = t & 63;
    unsigned int q = lane >> 4;
    unsigned int fl = lane & 15;     // feature pair (32+2fl, 32+2fl+1)
    float di = dinv[d];
    float a0 = 0.f, a1 = 0.f;
    if (q == 0) {
        unsigned int u = tbl[(unsigned int)d * 16u + fl];
        a0 = di * bf16lo(u); a1 = di * bf16hi(u);
    }
    int start = rowstart[d];
    int cnt = counts[d];
    int k = 0;
    for (; k + 16 <= cnt; k += 16) {
        unsigned int s0 = srcs[start + k + q];
        unsigned int s1 = srcs[start + k + 4 + q];
        unsigned int s2 = srcs[start + k + 8 + q];
        unsigned int s3 = srcs[start + k + 12 + q];
        float dv0 = dinv[s0], dv1 = dinv[s1], dv2 = dinv[s2], dv3 = dinv[s3];
        unsigned int u0 = tbl[s0 * 16u + fl];
        unsigned int u1 = tbl[s1 * 16u + fl];
        unsigned int u2 = tbl[s2 * 16u + fl];
        unsigned int u3 = tbl[s3 * 16u + fl];
        a0 = fmaf(dv0, bf16lo(u0), a0); a1 = fmaf(dv0, bf16hi(u0), a1);
        a0 = fmaf(dv1, bf16lo(u1), a0); a1 = fmaf(dv1, bf16hi(u1), a1);
        a0 = fmaf(dv2, bf16lo(u2), a0); a1 = fmaf(dv2, bf16hi(u2), a1);
        a0 = fmaf(dv3, bf16lo(u3), a0); a1 = fmaf(dv3, bf16hi(u3), a1);
    }
    for (; k + 8 <= cnt; k += 8) {
        unsigned int s0 = srcs[start + k + q];
        unsigned int s1 = srcs[start + k + 4 + q];
        float dv0 = dinv[s0], dv1 = dinv[s1];
        unsigned int u0 = tbl[s0 * 16u + fl];
        unsigned int u1 = tbl[s1 * 16u + fl];
        a0 = fmaf(dv0, bf16lo(u0), a0); a1 = fmaf(dv0, bf16hi(u0), a1);
        a0 = fmaf(dv1, bf16lo(u1), a0); a1 = fmaf(dv1, bf16hi(u1), a1);
    }
    for (; k < cnt; k += 4) {
        int idx = k + (int)q;
        if (idx < cnt) {
            unsigned int s0 = srcs[start + idx];
            float dv0 = dinv[s0];
            unsigned int u0 = tbl[s0 * 16u + fl];
            a0 = fmaf(dv0, bf16lo(u0), a0); a1 = fmaf(dv0, bf16hi(u0), a1);
        }
    }
    a0 += __shfl_xor(a0, 16); a0 += __shfl_xor(a0, 32);
    a1 += __shfl_xor(a1, 16); a1 += __shfl_xor(a1, 32);
    float2 bb = ((const float2*)(b + 32))[fl];
    float o2 = fmaxf(di * a0 + bb.x, 0.f);   // relu'd feat 32+2fl
    float o3 = fmaxf(di * a1 + bb.y, 0.f);   // relu'd feat 32+2fl+1
    // load pass-A relu'd feats (coalesced; every lane loads so all quarters hold them)
    unsigned int ulo = outA[(unsigned int)d * 16u + fl];
    float o0 = bf16lo(ulo);                  // feat 2fl
    float o1 = bf16hi(ulo);                  // feat 2fl+1

    // fused GEMM2: quarter q consumes feats kk = q*16 + j; holder lane within quarter
    int c = lane & 15;
    float acc = 0.f;
#pragma unroll
    for (int j = 0; j < 16; ++j) {
        int kk = (int)q * 16 + j;
        int srcl = (int)q * 16 + (((unsigned)kk & 31u) >> 1);
        float fvl = (j & 1) ? o1 : o0;       // feats 0-31 (q<2)
        float fvh = (j & 1) ? o3 : o2;       // feats 32-63 (q>=2)
        float fv = __shfl((q >= 2) ? fvh : fvl, srcl);
        acc += fv * W2s[kk * 17 + c];
    }
    acc += __shfl_xor(acc, 16);
    acc += __shfl_xor(acc, 32);
    if (lane < 16) h2b[(unsigned int)d * 16u + c] = bf16enc(di * acc);
}

// ------- CSR aggregation, 16 feats (bf16 h, scalar 8-unroll) + fused log_softmax ----
__global__ __launch_bounds__(256) void k_agg16(const int* __restrict__ rowstart,
                                               const int* __restrict__ counts,
                                               const unsigned int* __restrict__ srcs,
                                               const unsigned short* __restrict__ hb,
                                               const float* __restrict__ dinv,
                                               const float* __restrict__ b,
                                               float* __restrict__ out, int n) {
    int g = (blockIdx.x * 256 + threadIdx.x) >> 4;
    if (g >= n) return;
    unsigned int f = threadIdx.x & 15;
    float acc = bf16dec(hb[(unsigned int)g * 16u + f]);
    int start = rowstart[g];
    int cnt = counts[g];
    int k = 0;
    for (; k + 8 <= cnt; k += 8) {
        unsigned int s0 = srcs[start + k];
        unsigned int s1 = srcs[start + k + 1];
        unsigned int s2 = srcs[start + k + 2];
        unsigned int s3 = srcs[start + k + 3];
        unsigned int s4 = srcs[start + k + 4];
        unsigned int s5 = srcs[start + k + 5];
        unsigned int s6 = srcs[start + k + 6];
        unsigned int s7 = srcs[start + k + 7];
        unsigned short u0 = hb[s0 * 16u + f];
        unsigned short u1 = hb[s1 * 16u + f];
        unsigned short u2 = hb[s2 * 16u + f];
        unsigned short u3 = hb[s3 * 16u + f];
        unsigned short u4 = hb[s4 * 16u + f];
        unsigned short u5 = hb[s5 * 16u + f];
        unsigned short u6 = hb[s6 * 16u + f];
        unsigned short u7 = hb[s7 * 16u + f];
        acc += bf16dec(u0); acc += bf16dec(u1); acc += bf16dec(u2); acc += bf16dec(u3);
        acc += bf16dec(u4); acc += bf16dec(u5); acc += bf16dec(u6); acc += bf16dec(u7);
    }
    for (; k < cnt; ++k) acc += bf16dec(hb[srcs[start + k] * 16u + f]);
    float v = dinv[g] * acc + b[f];
    float m = v;
#pragma unroll
    for (int o = 8; o >= 1; o >>= 1) m = fmaxf(m, __shfl_xor(m, o, 16));
    float ex = __expf(v - m);
#pragma unroll
    for (int o = 8; o >= 1; o >>= 1) ex += __shfl_xor(ex, o, 16);
    out[(unsigned int)g * 16u + f] = (v - m) - __logf(ex);
}

extern "C" void kernel_launch(void* const* d_in, const int* in_sizes, int n_in,
                              void* d_out, int out_size, void* d_ws, size_t ws_size,
                              hipStream_t stream) {
    const float* x  = (const float*)d_in[0];
    const void*  ei = d_in[1];
    const float* W1 = (const float*)d_in[2];
    const float* b1 = (const float*)d_in[3];
    const float* W2 = (const float*)d_in[4];
    const float* b2 = (const float*)d_in[5];

    long long dh  = in_sizes[3];                 // 64
    long long din = in_sizes[2] / dh;            // 64
    long long n   = in_sizes[0] / din;           // 50000
    long long E   = (long long)in_sizes[1] / 2;  // 1.6M
    int nbuckets  = (int)((n + BNODES - 1) >> BSHIFT);  // 782

    // slice size: keep block count <= 256 (k_scanB width)
    long long epb = 8192;
    while ((E + epb - 1) / epb > 256) epb <<= 1;
    int nblk = (int)((E + epb - 1) / epb);       // 196 for E=1.6M
    int ngemm = (int)(n / 16);                   // 3125 gemm1 blocks

    char* ws = (char*)d_ws;
    auto alloc = [&](size_t bytes) { void* p = ws; ws += (bytes + 255) & ~255ULL; return p; };
    int*   totals   = (int*)alloc(nbuckets * 4);
    int*   base     = (int*)alloc(nbuckets * 4);
    int*   rowstart = (int*)alloc(n * 4);
    int*   counts   = (int*)alloc(n * 4);
    float* dinv     = (float*)alloc(n * 4);
    int*   partial  = (int*)alloc((size_t)nbuckets * nblk * 4);
    unsigned int* keys = (unsigned int*)alloc(E * 4);
    unsigned short* h1lo = (unsigned short*)alloc(n * 32 * 2);
    unsigned short* h1hi = (unsigned short*)alloc(n * 32 * 2);
    unsigned int*   outA = (unsigned int*)alloc(n * 32 * 2);
    unsigned short* h2b  = (unsigned short*)alloc(n * 16 * 2);
    unsigned int* sort_scratch = (unsigned int*)alloc(E * 4);  // big-bucket fallback

    float* out = (float*)d_out;

    // fat launch: hist (blocks 0..nblk) overlapped with gemm1 (rest)
    k_hist_gemm1<<<nblk + ngemm, 256, 0, stream>>>(ei, n, E, epb, nbuckets, nblk,
                                                   partial, x, W1, h1lo, h1hi);
    k_scanB<<<nbuckets, 256, 0, stream>>>(partial, nblk, totals);
    k_scan<<<1, 1024, 0, stream>>>(totals, nbuckets, base);
    k_place<<<nblk, 512, 0, stream>>>(ei, n, E, epb, nbuckets, nblk, base, partial, keys);
    k_sortdeg<<<nbuckets, 256, 0, stream>>>(keys, base, totals, rowstart, counts,
                                            dinv, (int)n, sort_scratch);

    // layer 1 aggregation in two L2-resident passes; pass B fuses the GEMM2
    k_agg64A<<<(int)((n * 64 + 255) / 256), 256, 0, stream>>>(
        rowstart, counts, keys, (const unsigned int*)h1lo, dinv, b1, outA, (int)n);
    k_agg64B<<<(int)((n * 64 + 255) / 256), 256, 0, stream>>>(
        rowstart, counts, keys, (const unsigned int*)h1hi, dinv, b1, W2, outA, h2b, (int)n);

    // layer 2 aggregation + log_softmax
    k_agg16<<<(int)((n * 16 + 255) / 256), 256, 0, stream>>>(
        rowstart, counts, keys, h2b, dinv, b2, out, (int)n);
}

// Round 20
// 123.249 us; speedup vs baseline: 1.0755x; 1.0755x over previous
//
#include <hip/hip_runtime.h>
#include <hip/hip_bf16.h>
#include <math.h>

// bucket = 64 consecutive dst nodes. key packs (dlow<<17 | src), valid for n < 131072.
#define BSHIFT 6
#define BNODES 64
#define MAXB 1024   // max buckets supported by single-block scan (n <= 65536)
#define SORTCAP 4096

// ---------------- inline dtype detection: int64 vs int32 edge_index ----------------
__device__ __forceinline__ bool detect_f64(const void* edges, long long nn) {
    const long long* e64 = (const long long*)edges;
    bool ok = true;
#pragma unroll
    for (int i = 0; i < 8; ++i) {
        long long v = e64[i];
        ok = ok && (v >= 0 && v < nn);
    }
    return ok;
}

__device__ __forceinline__ float bf16lo(unsigned int u) {
    return __uint_as_float(u << 16);
}
__device__ __forceinline__ float bf16hi(unsigned int u) {
    return __uint_as_float(u & 0xFFFF0000u);
}
__device__ __forceinline__ float bf16dec(unsigned short u) {
    return __uint_as_float(((unsigned int)u) << 16);
}
__device__ __forceinline__ unsigned short bf16enc(float f) {
    __hip_bfloat16 h = __float2bfloat16(f);
    return *reinterpret_cast<unsigned short*>(&h);
}

// ---- (A) FAT kernel: blocks [0,nblk) = per-slice histogram; rest = GEMM1 ----
__global__ __launch_bounds__(256) void k_hist_gemm1(const void* edges, long long nn,
                                                    long long E, long long epb,
                                                    int nbuckets, int nblk, int* partial,
                                                    const float* __restrict__ x,
                                                    const float* __restrict__ W1,
                                                    unsigned short* __restrict__ h1b) {
    __shared__ __align__(16) char smem[20480];   // hist: 4KB cnt | gemm1: 16KB Ws + 4KB xs
    int t = threadIdx.x;
    if (blockIdx.x < (unsigned int)nblk) {
        int* cnt = (int*)smem;
        int i = blockIdx.x;
        for (int b = t; b < nbuckets; b += 256) cnt[b] = 0;
        __syncthreads();
        bool f64 = detect_f64(edges, nn);
        long long e0 = (long long)i * epb;
        long long e1 = e0 + epb; if (e1 > E) e1 = E;
        for (long long e = e0 + t; e < e1; e += 256) {
            int d = f64 ? (int)((const long long*)edges)[E + e] : ((const int*)edges)[E + e];
            atomicAdd(&cnt[d >> BSHIFT], 1);
        }
        __syncthreads();
        for (int b = t; b < nbuckets; b += 256) partial[b * nblk + i] = cnt[b];
    } else {
        float (*Ws)[64] = (float(*)[64])smem;
        float (*xs)[64] = (float(*)[64])(smem + 64 * 64 * 4);
        for (int i = t; i < 64 * 64; i += 256) Ws[i >> 6][i & 63] = W1[i];
        long long row0 = (long long)(blockIdx.x - nblk) * 16;
        ((float4*)xs)[t] = ((const float4*)(x + row0 * 64))[t];
        __syncthreads();
        int r = t >> 4, c0 = (t & 15) * 4;
        float4 acc = {0.f, 0.f, 0.f, 0.f};
#pragma unroll
        for (int k = 0; k < 64; ++k) {
            float xv = xs[r][k];
            float4 wv = *((const float4*)&Ws[k][c0]);
            acc.x += xv * wv.x; acc.y += xv * wv.y;
            acc.z += xv * wv.z; acc.w += xv * wv.w;
        }
        ushort4 pk;
        pk.x = bf16enc(acc.x);
        pk.y = bf16enc(acc.y);
        pk.z = bf16enc(acc.z);
        pk.w = bf16enc(acc.w);
        *((ushort4*)(h1b + (row0 + r) * 64 + c0)) = pk;
    }
}

// ---- (B) per-bucket exclusive scan over blocks (chunked, carry); emits totals ----
__global__ __launch_bounds__(256) void k_scanB(int* partial, int nblk, int* totals) {
    __shared__ int tmp[256];
    int b = blockIdx.x, t = threadIdx.x;
    int carry = 0;
    for (int c0 = 0; c0 < nblk; c0 += 256) {
        int idx = c0 + t;
        int v = (idx < nblk) ? partial[b * nblk + idx] : 0;
        tmp[t] = v;
        __syncthreads();
        for (int off = 1; off < 256; off <<= 1) {
            int a = (t >= off) ? tmp[t - off] : 0;
            __syncthreads();
            tmp[t] += a;
            __syncthreads();
        }
        if (idx < nblk) partial[b * nblk + idx] = carry + tmp[t] - v;  // exclusive
        carry += tmp[255];
        __syncthreads();
    }
    if (t == 0) totals[b] = carry;
}

// ---- (C) bucket-level exclusive scan: base = exclusive(totals) ----
__global__ __launch_bounds__(1024) void k_scan(const int* __restrict__ totals, int nbuckets,
                                               int* base) {
    __shared__ int tmp[MAXB];
    int t = threadIdx.x;
    int v = (t < nbuckets) ? totals[t] : 0;
    tmp[t] = v;
    __syncthreads();
    for (int off = 1; off < MAXB; off <<= 1) {
        int a = (t >= off) ? tmp[t - off] : 0;
        __syncthreads();
        tmp[t] += a;
        __syncthreads();
    }
    if (t < nbuckets) base[t] = tmp[t] - v;
}

// ---- (D) place keys: LDS cursors seeded from base+partial; no global atomics ----
__global__ __launch_bounds__(512) void k_place(const void* edges, long long nn,
                                               long long E, long long epb,
                                               int nbuckets, int nblk,
                                               const int* __restrict__ base,
                                               const int* __restrict__ partial,
                                               unsigned int* keys) {
    __shared__ int cur[MAXB];
    int t = threadIdx.x;
    int i = blockIdx.x;
    for (int b = t; b < nbuckets; b += 512) cur[b] = base[b] + partial[b * nblk + i];
    __syncthreads();
    bool f64 = detect_f64(edges, nn);
    long long e0 = (long long)i * epb;
    long long e1 = e0 + epb; if (e1 > E) e1 = E;
    for (long long e = e0 + t; e < e1; e += 512) {
        int s, d;
        if (f64) {
            const long long* ee = (const long long*)edges;
            s = (int)ee[e]; d = (int)ee[E + e];
        } else {
            const int* ee = (const int*)edges;
            s = ee[e]; d = ee[E + e];
        }
        int pos = atomicAdd(&cur[d >> BSHIFT], 1);
        keys[pos] = (unsigned int)s | ((unsigned int)(d & (BNODES - 1)) << 17);
    }
}

// -------- per-bucket LDS counting sort -> node-exact CSR; fuses deg/dinv --------
__global__ __launch_bounds__(256) void k_sortdeg(unsigned int* keys,
                                                 const int* __restrict__ base,
                                                 const int* __restrict__ totals,
                                                 int* rowstart, int* counts,
                                                 float* dinv, int n,
                                                 unsigned int* scratch) {
    __shared__ unsigned int kbuf[SORTCAP];
    __shared__ int hist[BNODES];
    __shared__ int cur[BNODES];
    int t = threadIdx.x;
    int bk = blockIdx.x;
    int st = base[bk], c = totals[bk];
    if (t < BNODES) hist[t] = 0;
    __syncthreads();
    bool fits = (c <= SORTCAP);
    if (fits) {
        for (int i = t; i < c; i += 256) {
            unsigned int k = keys[st + i];
            kbuf[i] = k;
            atomicAdd(&hist[k >> 17], 1);
        }
    } else {  // statistically never for random edges; correct fallback via global scratch
        for (int i = t; i < c; i += 256) {
            unsigned int k = keys[st + i];
            scratch[st + i] = k;
            atomicAdd(&hist[k >> 17], 1);
        }
    }
    __syncthreads();
    if (t < 64) {  // wave 0: scan 64 counters
        int v = hist[t];
        int incl = v;
        for (int o = 1; o < 64; o <<= 1) {
            int other = __shfl_up(incl, o, 64);
            if (t >= o) incl += other;
        }
        int ex = incl - v;
        cur[t] = ex;
        int node = bk * BNODES + t;
        if (node < n) {
            rowstart[node] = st + ex;
            counts[node] = v;
            dinv[node] = rsqrtf((float)v + 1.0f);
        }
    }
    __syncthreads();
    if (fits) {
        for (int i = t; i < c; i += 256) {
            unsigned int k = kbuf[i];
            int pos = atomicAdd(&cur[k >> 17], 1);
            keys[st + pos] = k & 0x1FFFFu;
        }
    } else {
        for (int i = t; i < c; i += 256) {
            unsigned int k = scratch[st + i];
            int pos = atomicAdd(&cur[k >> 17], 1);
            keys[st + pos] = k & 0x1FFFFu;
        }
    }
}

// ------- CSR aggregation, 64 feats (bf16, 4-wide, dinv-FMA) + FUSED GEMM2 -------
__global__ __launch_bounds__(256) void k_agg64(const int* __restrict__ rowstart,
                                               const int* __restrict__ counts,
                                               const unsigned int* __restrict__ srcs,
                                               const uint2* __restrict__ hb4,
                                               const float* __restrict__ dinv,
                                               const float* __restrict__ b,
                                               const float* __restrict__ W2,
                                               unsigned short* __restrict__ h2b, int n) {
    __shared__ float W2s[64 * 17];
    int t = threadIdx.x;
    for (int i = t; i < 64 * 16; i += 256) W2s[(i >> 4) * 17 + (i & 15)] = W2[i];
    __syncthreads();  // before any divergence; all waves hit this immediately

    int d = (blockIdx.x * 256 + t) >> 6;
    if (d >= n) return;
    int lane = t & 63;
    unsigned int q = lane >> 4;      // quarter: edge offset 0..3
    unsigned int fl = lane & 15;     // feature-quad index (feats 4fl..4fl+3)
    float di = dinv[d];
    float a0 = 0.f, a1 = 0.f, a2 = 0.f, a3 = 0.f;
    if (q == 0) {                    // self-loop: dinv[d] * h1[d]
        uint2 u = hb4[(unsigned int)d * 16u + fl];
        a0 = di * bf16lo(u.x); a1 = di * bf16hi(u.x);
        a2 = di * bf16lo(u.y); a3 = di * bf16hi(u.y);
    }
    int start = rowstart[d];
    int cnt = counts[d];
    int k = 0;
    for (; k + 16 <= cnt; k += 16) {
        unsigned int s0 = srcs[start + k + q];
        unsigned int s1 = srcs[start + k + 4 + q];
        unsigned int s2 = srcs[start + k + 8 + q];
        unsigned int s3 = srcs[start + k + 12 + q];
        float dv0 = dinv[s0];
        float dv1 = dinv[s1];
        float dv2 = dinv[s2];
        float dv3 = dinv[s3];
        uint2 u0 = hb4[s0 * 16u + fl];
        uint2 u1 = hb4[s1 * 16u + fl];
        uint2 u2 = hb4[s2 * 16u + fl];
        uint2 u3 = hb4[s3 * 16u + fl];
        a0 = fmaf(dv0, bf16lo(u0.x), a0); a1 = fmaf(dv0, bf16hi(u0.x), a1);
        a2 = fmaf(dv0, bf16lo(u0.y), a2); a3 = fmaf(dv0, bf16hi(u0.y), a3);
        a0 = fmaf(dv1, bf16lo(u1.x), a0); a1 = fmaf(dv1, bf16hi(u1.x), a1);
        a2 = fmaf(dv1, bf16lo(u1.y), a2); a3 = fmaf(dv1, bf16hi(u1.y), a3);
        a0 = fmaf(dv2, bf16lo(u2.x), a0); a1 = fmaf(dv2, bf16hi(u2.x), a1);
        a2 = fmaf(dv2, bf16lo(u2.y), a2); a3 = fmaf(dv2, bf16hi(u2.y), a3);
        a0 = fmaf(dv3, bf16lo(u3.x), a0); a1 = fmaf(dv3, bf16hi(u3.x), a1);
        a2 = fmaf(dv3, bf16lo(u3.y), a2); a3 = fmaf(dv3, bf16hi(u3.y), a3);
    }
    for (; k + 8 <= cnt; k += 8) {
        unsigned int s0 = srcs[start + k + q];
        unsigned int s1 = srcs[start + k + 4 + q];
        float dv0 = dinv[s0];
        float dv1 = dinv[s1];
        uint2 u0 = hb4[s0 * 16u + fl];
        uint2 u1 = hb4[s1 * 16u + fl];
        a0 = fmaf(dv0, bf16lo(u0.x), a0); a1 = fmaf(dv0, bf16hi(u0.x), a1);
        a2 = fmaf(dv0, bf16lo(u0.y), a2); a3 = fmaf(dv0, bf16hi(u0.y), a3);
        a0 = fmaf(dv1, bf16lo(u1.x), a0); a1 = fmaf(dv1, bf16hi(u1.x), a1);
        a2 = fmaf(dv1, bf16lo(u1.y), a2); a3 = fmaf(dv1, bf16hi(u1.y), a3);
    }
    for (; k < cnt; k += 4) {
        int idx = k + (int)q;
        if (idx < cnt) {
            unsigned int s0 = srcs[start + idx];
            float dv0 = dinv[s0];
            uint2 u0 = hb4[s0 * 16u + fl];
            a0 = fmaf(dv0, bf16lo(u0.x), a0); a1 = fmaf(dv0, bf16hi(u0.x), a1);
            a2 = fmaf(dv0, bf16lo(u0.y), a2); a3 = fmaf(dv0, bf16hi(u0.y), a3);
        }
    }
    // combine quarters (lanes with equal fl: xor 16, 32); all lanes hold totals
    a0 += __shfl_xor(a0, 16); a0 += __shfl_xor(a0, 32);
    a1 += __shfl_xor(a1, 16); a1 += __shfl_xor(a1, 32);
    a2 += __shfl_xor(a2, 16); a2 += __shfl_xor(a2, 32);
    a3 += __shfl_xor(a3, 16); a3 += __shfl_xor(a3, 32);
    float4 bb = ((const float4*)b)[fl];
    float o0 = fmaxf(di * a0 + bb.x, 0.f);   // relu'd feat 4fl+0
    float o1 = fmaxf(di * a1 + bb.y, 0.f);
    float o2 = fmaxf(di * a2 + bb.z, 0.f);
    float o3 = fmaxf(di * a3 + bb.w, 0.f);

    // fused GEMM2: lane computes partial dot for col c over its quarter's 16 feats
    int c = lane & 15;
    float acc = 0.f;
#pragma unroll
    for (int j = 0; j < 16; ++j) {
        int kk = (int)q * 16 + j;            // feat index this lane consumes
        int srcl = (int)q * 20 + (j >> 2);   // q*16 + (kk>>2): holder within quarter
        float fv;
        if ((j & 3) == 0)      fv = __shfl(o0, srcl);
        else if ((j & 3) == 1) fv = __shfl(o1, srcl);
        else if ((j & 3) == 2) fv = __shfl(o2, srcl);
        else                   fv = __shfl(o3, srcl);
        acc += fv * W2s[kk * 17 + c];
    }
    acc += __shfl_xor(acc, 16);
    acc += __shfl_xor(acc, 32);
    if (lane < 16) h2b[(unsigned int)d * 16u + c] = bf16enc(di * acc);
}

// ------- CSR aggregation, 16 feats (bf16 h, scalar 8-unroll) + fused log_softmax ----
__global__ __launch_bounds__(256) void k_agg16(const int* __restrict__ rowstart,
                                               const int* __restrict__ counts,
                                               const unsigned int* __restrict__ srcs,
                                               const unsigned short* __restrict__ hb,
                                               const float* __restrict__ dinv,
                                               const float* __restrict__ b,
                                               float* __restrict__ out, int n) {
    int g = (blockIdx.x * 256 + threadIdx.x) >> 4;
    if (g >= n) return;
    unsigned int f = threadIdx.x & 15;
    float acc = bf16dec(hb[(unsigned int)g * 16u + f]);
    int start = rowstart[g];
    int cnt = counts[g];
    int k = 0;
    for (; k + 8 <= cnt; k += 8) {
        unsigned int s0 = srcs[start + k];
        unsigned int s1 = srcs[start + k + 1];
        unsigned int s2 = srcs[start + k + 2];
        unsigned int s3 = srcs[start + k + 3];
        unsigned int s4 = srcs[start + k + 4];
        unsigned int s5 = srcs[start + k + 5];
        unsigned int s6 = srcs[start + k + 6];
        unsigned int s7 = srcs[start + k + 7];
        unsigned short u0 = hb[s0 * 16u + f];
        unsigned short u1 = hb[s1 * 16u + f];
        unsigned short u2 = hb[s2 * 16u + f];
        unsigned short u3 = hb[s3 * 16u + f];
        unsigned short u4 = hb[s4 * 16u + f];
        unsigned short u5 = hb[s5 * 16u + f];
        unsigned short u6 = hb[s6 * 16u + f];
        unsigned short u7 = hb[s7 * 16u + f];
        acc += bf16dec(u0); acc += bf16dec(u1); acc += bf16dec(u2); acc += bf16dec(u3);
        acc += bf16dec(u4); acc += bf16dec(u5); acc += bf16dec(u6); acc += bf16dec(u7);
    }
    for (; k < cnt; ++k) acc += bf16dec(hb[srcs[start + k] * 16u + f]);
    float v = dinv[g] * acc + b[f];
    float m = v;
#pragma unroll
    for (int o = 8; o >= 1; o >>= 1) m = fmaxf(m, __shfl_xor(m, o, 16));
    float ex = __expf(v - m);
#pragma unroll
    for (int o = 8; o >= 1; o >>= 1) ex += __shfl_xor(ex, o, 16);
    out[(unsigned int)g * 16u + f] = (v - m) - __logf(ex);
}

extern "C" void kernel_launch(void* const* d_in, const int* in_sizes, int n_in,
                              void* d_out, int out_size, void* d_ws, size_t ws_size,
                              hipStream_t stream) {
    const float* x  = (const float*)d_in[0];
    const void*  ei = d_in[1];
    const float* W1 = (const float*)d_in[2];
    const float* b1 = (const float*)d_in[3];
    const float* W2 = (const float*)d_in[4];
    const float* b2 = (const float*)d_in[5];

    long long dh  = in_sizes[3];                 // 64
    long long din = in_sizes[2] / dh;            // 64
    long long n   = in_sizes[0] / din;           // 50000
    long long E   = (long long)in_sizes[1] / 2;  // 1.6M
    int nbuckets  = (int)((n + BNODES - 1) >> BSHIFT);  // 782

    // slice size: ~3 blocks/CU for hist/place; scanB loops over nblk in 256-chunks
    long long epb = 2048;
    while ((E + epb - 1) / epb > 1024) epb <<= 1;
    int nblk = (int)((E + epb - 1) / epb);       // 782 for E=1.6M
    int ngemm = (int)(n / 16);                   // 3125 gemm1 blocks

    char* ws = (char*)d_ws;
    auto alloc = [&](size_t bytes) { void* p = ws; ws += (bytes + 255) & ~255ULL; return p; };
    int*   totals   = (int*)alloc(nbuckets * 4);
    int*   base     = (int*)alloc(nbuckets * 4);
    int*   rowstart = (int*)alloc(n * 4);
    int*   counts   = (int*)alloc(n * 4);
    float* dinv     = (float*)alloc(n * 4);
    int*   partial  = (int*)alloc((size_t)nbuckets * nblk * 4);
    unsigned int* keys = (unsigned int*)alloc(E * 4);
    unsigned short* h1b  = (unsigned short*)alloc(n * 64 * 2);
    unsigned short* h2b  = (unsigned short*)alloc(n * 16 * 2);
    unsigned int* sort_scratch = (unsigned int*)alloc(E * 4);  // big-bucket fallback

    float* out = (float*)d_out;

    // fat launch: hist (blocks 0..nblk) overlapped with gemm1 (rest)
    k_hist_gemm1<<<nblk + ngemm, 256, 0, stream>>>(ei, n, E, epb, nbuckets, nblk,
                                                   partial, x, W1, h1b);
    k_scanB<<<nbuckets, 256, 0, stream>>>(partial, nblk, totals);
    k_scan<<<1, 1024, 0, stream>>>(totals, nbuckets, base);
    k_place<<<nblk, 512, 0, stream>>>(ei, n, E, epb, nbuckets, nblk, base, partial, keys);
    k_sortdeg<<<nbuckets, 256, 0, stream>>>(keys, base, totals, rowstart, counts,
                                            dinv, (int)n, sort_scratch);

    // layer 1 aggregation (+ fused layer-2 GEMM in epilogue)
    k_agg64<<<(int)((n * 64 + 255) / 256), 256, 0, stream>>>(
        rowstart, counts, keys, (const uint2*)h1b, dinv, b1, W2, h2b, (int)n);

    // layer 2 aggregation + log_softmax
    k_agg16<<<(int)((n * 16 + 255) / 256), 256, 0, stream>>>(
        rowstart, counts, keys, h2b, dinv, b2, out, (int)n);
}

// Round 21
// 110.596 us; speedup vs baseline: 1.1985x; 1.1144x over previous
//
#include <hip/hip_runtime.h>
#include <hip/hip_bf16.h>
#include <math.h>

// bucket = 64 consecutive dst nodes. key packs (dlow<<17 | src), valid for n < 131072.
#define BSHIFT 6
#define BNODES 64
#define MAXB 1024   // max buckets supported by single-block scan (n <= 65536)
#define SORTCAP 4096

// ---------------- inline dtype detection: int64 vs int32 edge_index ----------------
__device__ __forceinline__ bool detect_f64(const void* edges, long long nn) {
    const long long* e64 = (const long long*)edges;
    bool ok = true;
#pragma unroll
    for (int i = 0; i < 8; ++i) {
        long long v = e64[i];
        ok = ok && (v >= 0 && v < nn);
    }
    return ok;
}

__device__ __forceinline__ float bf16lo(unsigned int u) {
    return __uint_as_float(u << 16);
}
__device__ __forceinline__ float bf16hi(unsigned int u) {
    return __uint_as_float(u & 0xFFFF0000u);
}
__device__ __forceinline__ float bf16dec(unsigned short u) {
    return __uint_as_float(((unsigned int)u) << 16);
}
__device__ __forceinline__ unsigned short bf16enc(float f) {
    __hip_bfloat16 h = __float2bfloat16(f);
    return *reinterpret_cast<unsigned short*>(&h);
}

// ---- (A) FAT kernel: blocks [0,nblk) = per-slice histogram; rest = GEMM1 ----
// hist: LDS histogram of dst buckets -> partial[b*nblk+i] (plain stores).
// gemm1: h1b[n,64](bf16) = x[n,64] @ W1[64,64]  (UNSCALED; dinv folded into agg64)
// Independent work overlapped in one launch.
__global__ __launch_bounds__(256) void k_hist_gemm1(const void* edges, long long nn,
                                                    long long E, long long epb,
                                                    int nbuckets, int nblk, int* partial,
                                                    const float* __restrict__ x,
                                                    const float* __restrict__ W1,
                                                    unsigned short* __restrict__ h1b) {
    __shared__ __align__(16) char smem[20480];   // hist: 4KB cnt | gemm1: 16KB Ws + 4KB xs
    int t = threadIdx.x;
    if (blockIdx.x < (unsigned int)nblk) {
        int* cnt = (int*)smem;
        int i = blockIdx.x;
        for (int b = t; b < nbuckets; b += 256) cnt[b] = 0;
        __syncthreads();
        bool f64 = detect_f64(edges, nn);
        long long e0 = (long long)i * epb;
        long long e1 = e0 + epb; if (e1 > E) e1 = E;
        for (long long e = e0 + t; e < e1; e += 256) {
            int d = f64 ? (int)((const long long*)edges)[E + e] : ((const int*)edges)[E + e];
            atomicAdd(&cnt[d >> BSHIFT], 1);
        }
        __syncthreads();
        for (int b = t; b < nbuckets; b += 256) partial[b * nblk + i] = cnt[b];
    } else {
        float (*Ws)[64] = (float(*)[64])smem;
        float (*xs)[64] = (float(*)[64])(smem + 64 * 64 * 4);
        for (int i = t; i < 64 * 64; i += 256) Ws[i >> 6][i & 63] = W1[i];
        long long row0 = (long long)(blockIdx.x - nblk) * 16;
        ((float4*)xs)[t] = ((const float4*)(x + row0 * 64))[t];
        __syncthreads();
        int r = t >> 4, c0 = (t & 15) * 4;
        float4 acc = {0.f, 0.f, 0.f, 0.f};
#pragma unroll
        for (int k = 0; k < 64; ++k) {
            float xv = xs[r][k];
            float4 wv = *((const float4*)&Ws[k][c0]);
            acc.x += xv * wv.x; acc.y += xv * wv.y;
            acc.z += xv * wv.z; acc.w += xv * wv.w;
        }
        ushort4 pk;
        pk.x = bf16enc(acc.x);
        pk.y = bf16enc(acc.y);
        pk.z = bf16enc(acc.z);
        pk.w = bf16enc(acc.w);
        *((ushort4*)(h1b + (row0 + r) * 64 + c0)) = pk;
    }
}

// ---- (B) per-bucket exclusive scan over blocks; emits bucket totals ----
__global__ __launch_bounds__(256) void k_scanB(int* partial, int nblk, int* totals) {
    __shared__ int tmp[256];
    int b = blockIdx.x, t = threadIdx.x;
    int v = (t < nblk) ? partial[b * nblk + t] : 0;
    tmp[t] = v;
    __syncthreads();
    for (int off = 1; off < 256; off <<= 1) {
        int a = (t >= off) ? tmp[t - off] : 0;
        __syncthreads();
        tmp[t] += a;
        __syncthreads();
    }
    if (t < nblk) partial[b * nblk + t] = tmp[t] - v;  // exclusive over blocks
    if (t == 255) totals[b] = tmp[255];
}

// ---- (C) bucket-level exclusive scan: base = exclusive(totals) ----
__global__ __launch_bounds__(1024) void k_scan(const int* __restrict__ totals, int nbuckets,
                                               int* base) {
    __shared__ int tmp[MAXB];
    int t = threadIdx.x;
    int v = (t < nbuckets) ? totals[t] : 0;
    tmp[t] = v;
    __syncthreads();
    for (int off = 1; off < MAXB; off <<= 1) {
        int a = (t >= off) ? tmp[t - off] : 0;
        __syncthreads();
        tmp[t] += a;
        __syncthreads();
    }
    if (t < nbuckets) base[t] = tmp[t] - v;
}

// ---- (D) place keys: LDS cursors seeded from base+partial; no global atomics ----
__global__ __launch_bounds__(512) void k_place(const void* edges, long long nn,
                                               long long E, long long epb,
                                               int nbuckets, int nblk,
                                               const int* __restrict__ base,
                                               const int* __restrict__ partial,
                                               unsigned int* keys) {
    __shared__ int cur[MAXB];
    int t = threadIdx.x;
    int i = blockIdx.x;
    for (int b = t; b < nbuckets; b += 512) cur[b] = base[b] + partial[b * nblk + i];
    __syncthreads();
    bool f64 = detect_f64(edges, nn);
    long long e0 = (long long)i * epb;
    long long e1 = e0 + epb; if (e1 > E) e1 = E;
    for (long long e = e0 + t; e < e1; e += 512) {
        int s, d;
        if (f64) {
            const long long* ee = (const long long*)edges;
            s = (int)ee[e]; d = (int)ee[E + e];
        } else {
            const int* ee = (const int*)edges;
            s = ee[e]; d = ee[E + e];
        }
        int pos = atomicAdd(&cur[d >> BSHIFT], 1);
        keys[pos] = (unsigned int)s | ((unsigned int)(d & (BNODES - 1)) << 17);
    }
}

// -------- per-bucket LDS counting sort -> node-exact CSR; fuses deg/dinv --------
__global__ __launch_bounds__(256) void k_sortdeg(unsigned int* keys,
                                                 const int* __restrict__ base,
                                                 const int* __restrict__ totals,
                                                 int* rowstart, int* counts,
                                                 float* dinv, int n,
                                                 unsigned int* scratch) {
    __shared__ unsigned int kbuf[SORTCAP];
    __shared__ int hist[BNODES];
    __shared__ int cur[BNODES];
    int t = threadIdx.x;
    int bk = blockIdx.x;
    int st = base[bk], c = totals[bk];
    if (t < BNODES) hist[t] = 0;
    __syncthreads();
    bool fits = (c <= SORTCAP);
    if (fits) {
        for (int i = t; i < c; i += 256) {
            unsigned int k = keys[st + i];
            kbuf[i] = k;
            atomicAdd(&hist[k >> 17], 1);
        }
    } else {  // statistically never for random edges; correct fallback via global scratch
        for (int i = t; i < c; i += 256) {
            unsigned int k = keys[st + i];
            scratch[st + i] = k;
            atomicAdd(&hist[k >> 17], 1);
        }
    }
    __syncthreads();
    if (t < 64) {  // wave 0: scan 64 counters
        int v = hist[t];
        int incl = v;
        for (int o = 1; o < 64; o <<= 1) {
            int other = __shfl_up(incl, o, 64);
            if (t >= o) incl += other;
        }
        int ex = incl - v;
        cur[t] = ex;
        int node = bk * BNODES + t;
        if (node < n) {
            rowstart[node] = st + ex;
            counts[node] = v;
            dinv[node] = rsqrtf((float)v + 1.0f);
        }
    }
    __syncthreads();
    if (fits) {
        for (int i = t; i < c; i += 256) {
            unsigned int k = kbuf[i];
            int pos = atomicAdd(&cur[k >> 17], 1);
            keys[st + pos] = k & 0x1FFFFu;
        }
    } else {
        for (int i = t; i < c; i += 256) {
            unsigned int k = scratch[st + i];
            int pos = atomicAdd(&cur[k >> 17], 1);
            keys[st + pos] = k & 0x1FFFFu;
        }
    }
}

// ------- CSR aggregation, 64 feats (bf16, 4-wide, dinv-FMA) + FUSED GEMM2 -------
// h1b is UNSCALED; per edge multiply by dinv[s] (broadcast load, fma replaces add).
// 16 lanes x uint2 (8B) cover a 128B row; quarter-waves process edges k+0..k+3.
__global__ __launch_bounds__(256) void k_agg64(const int* __restrict__ rowstart,
                                               const int* __restrict__ counts,
                                               const unsigned int* __restrict__ srcs,
                                               const uint2* __restrict__ hb4,
                                               const float* __restrict__ dinv,
                                               const float* __restrict__ b,
                                               const float* __restrict__ W2,
                                               unsigned short* __restrict__ h2b, int n) {
    __shared__ float W2s[64 * 17];
    int t = threadIdx.x;
    for (int i = t; i < 64 * 16; i += 256) W2s[(i >> 4) * 17 + (i & 15)] = W2[i];
    __syncthreads();  // before any divergence; all waves hit this immediately

    int d = (blockIdx.x * 256 + t) >> 6;
    if (d >= n) return;
    int lane = t & 63;
    unsigned int q = lane >> 4;      // quarter: edge offset 0..3
    unsigned int fl = lane & 15;     // feature-quad index (feats 4fl..4fl+3)
    float di = dinv[d];
    float a0 = 0.f, a1 = 0.f, a2 = 0.f, a3 = 0.f;
    if (q == 0) {                    // self-loop: dinv[d] * h1[d]
        uint2 u = hb4[(unsigned int)d * 16u + fl];
        a0 = di * bf16lo(u.x); a1 = di * bf16hi(u.x);
        a2 = di * bf16lo(u.y); a3 = di * bf16hi(u.y);
    }
    int start = rowstart[d];
    int cnt = counts[d];
    int k = 0;
    for (; k + 16 <= cnt; k += 16) {
        unsigned int s0 = srcs[start + k + q];
        unsigned int s1 = srcs[start + k + 4 + q];
        unsigned int s2 = srcs[start + k + 8 + q];
        unsigned int s3 = srcs[start + k + 12 + q];
        float dv0 = dinv[s0];
        float dv1 = dinv[s1];
        float dv2 = dinv[s2];
        float dv3 = dinv[s3];
        uint2 u0 = hb4[s0 * 16u + fl];
        uint2 u1 = hb4[s1 * 16u + fl];
        uint2 u2 = hb4[s2 * 16u + fl];
        uint2 u3 = hb4[s3 * 16u + fl];
        a0 = fmaf(dv0, bf16lo(u0.x), a0); a1 = fmaf(dv0, bf16hi(u0.x), a1);
        a2 = fmaf(dv0, bf16lo(u0.y), a2); a3 = fmaf(dv0, bf16hi(u0.y), a3);
        a0 = fmaf(dv1, bf16lo(u1.x), a0); a1 = fmaf(dv1, bf16hi(u1.x), a1);
        a2 = fmaf(dv1, bf16lo(u1.y), a2); a3 = fmaf(dv1, bf16hi(u1.y), a3);
        a0 = fmaf(dv2, bf16lo(u2.x), a0); a1 = fmaf(dv2, bf16hi(u2.x), a1);
        a2 = fmaf(dv2, bf16lo(u2.y), a2); a3 = fmaf(dv2, bf16hi(u2.y), a3);
        a0 = fmaf(dv3, bf16lo(u3.x), a0); a1 = fmaf(dv3, bf16hi(u3.x), a1);
        a2 = fmaf(dv3, bf16lo(u3.y), a2); a3 = fmaf(dv3, bf16hi(u3.y), a3);
    }
    for (; k + 8 <= cnt; k += 8) {
        unsigned int s0 = srcs[start + k + q];
        unsigned int s1 = srcs[start + k + 4 + q];
        float dv0 = dinv[s0];
        float dv1 = dinv[s1];
        uint2 u0 = hb4[s0 * 16u + fl];
        uint2 u1 = hb4[s1 * 16u + fl];
        a0 = fmaf(dv0, bf16lo(u0.x), a0); a1 = fmaf(dv0, bf16hi(u0.x), a1);
        a2 = fmaf(dv0, bf16lo(u0.y), a2); a3 = fmaf(dv0, bf16hi(u0.y), a3);
        a0 = fmaf(dv1, bf16lo(u1.x), a0); a1 = fmaf(dv1, bf16hi(u1.x), a1);
        a2 = fmaf(dv1, bf16lo(u1.y), a2); a3 = fmaf(dv1, bf16hi(u1.y), a3);
    }
    for (; k < cnt; k += 4) {
        int idx = k + (int)q;
        if (idx < cnt) {
            unsigned int s0 = srcs[start + idx];
            float dv0 = dinv[s0];
            uint2 u0 = hb4[s0 * 16u + fl];
            a0 = fmaf(dv0, bf16lo(u0.x), a0); a1 = fmaf(dv0, bf16hi(u0.x), a1);
            a2 = fmaf(dv0, bf16lo(u0.y), a2); a3 = fmaf(dv0, bf16hi(u0.y), a3);
        }
    }
    // combine quarters (lanes with equal fl: xor 16, 32); all lanes hold totals
    a0 += __shfl_xor(a0, 16); a0 += __shfl_xor(a0, 32);
    a1 += __shfl_xor(a1, 16); a1 += __shfl_xor(a1, 32);
    a2 += __shfl_xor(a2, 16); a2 += __shfl_xor(a2, 32);
    a3 += __shfl_xor(a3, 16); a3 += __shfl_xor(a3, 32);
    float4 bb = ((const float4*)b)[fl];
    float o0 = fmaxf(di * a0 + bb.x, 0.f);   // relu'd feat 4fl+0
    float o1 = fmaxf(di * a1 + bb.y, 0.f);
    float o2 = fmaxf(di * a2 + bb.z, 0.f);
    float o3 = fmaxf(di * a3 + bb.w, 0.f);

    // fused GEMM2: lane computes partial dot for col c over its quarter's 16 feats
    int c = lane & 15;
    float acc = 0.f;
#pragma unroll
    for (int j = 0; j < 16; ++j) {
        int kk = (int)q * 16 + j;            // feat index this lane consumes
        int srcl = (int)q * 20 + (j >> 2);   // q*16 + (kk>>2): holder within quarter
        float fv;
        if ((j & 3) == 0)      fv = __shfl(o0, srcl);
        else if ((j & 3) == 1) fv = __shfl(o1, srcl);
        else if ((j & 3) == 2) fv = __shfl(o2, srcl);
        else                   fv = __shfl(o3, srcl);
        acc += fv * W2s[kk * 17 + c];
    }
    acc += __shfl_xor(acc, 16);
    acc += __shfl_xor(acc, 32);
    if (lane < 16) h2b[(unsigned int)d * 16u + c] = bf16enc(di * acc);
}

// ------- CSR aggregation, 16 feats (bf16 h, scalar 8-unroll) + fused log_softmax ----
__global__ __launch_bounds__(256) void k_agg16(const int* __restrict__ rowstart,
                                               const int* __restrict__ counts,
                                               const unsigned int* __restrict__ srcs,
                                               const unsigned short* __restrict__ hb,
                                               const float* __restrict__ dinv,
                                               const float* __restrict__ b,
                                               float* __restrict__ out, int n) {
    int g = (blockIdx.x * 256 + threadIdx.x) >> 4;
    if (g >= n) return;
    unsigned int f = threadIdx.x & 15;
    float acc = bf16dec(hb[(unsigned int)g * 16u + f]);
    int start = rowstart[g];
    int cnt = counts[g];
    int k = 0;
    for (; k + 8 <= cnt; k += 8) {
        unsigned int s0 = srcs[start + k];
        unsigned int s1 = srcs[start + k + 1];
        unsigned int s2 = srcs[start + k + 2];
        unsigned int s3 = srcs[start + k + 3];
        unsigned int s4 = srcs[start + k + 4];
        unsigned int s5 = srcs[start + k + 5];
        unsigned int s6 = srcs[start + k + 6];
        unsigned int s7 = srcs[start + k + 7];
        unsigned short u0 = hb[s0 * 16u + f];
        unsigned short u1 = hb[s1 * 16u + f];
        unsigned short u2 = hb[s2 * 16u + f];
        unsigned short u3 = hb[s3 * 16u + f];
        unsigned short u4 = hb[s4 * 16u + f];
        unsigned short u5 = hb[s5 * 16u + f];
        unsigned short u6 = hb[s6 * 16u + f];
        unsigned short u7 = hb[s7 * 16u + f];
        acc += bf16dec(u0); acc += bf16dec(u1); acc += bf16dec(u2); acc += bf16dec(u3);
        acc += bf16dec(u4); acc += bf16dec(u5); acc += bf16dec(u6); acc += bf16dec(u7);
    }
    for (; k < cnt; ++k) acc += bf16dec(hb[srcs[start + k] * 16u + f]);
    float v = dinv[g] * acc + b[f];
    float m = v;
#pragma unroll
    for (int o = 8; o >= 1; o >>= 1) m = fmaxf(m, __shfl_xor(m, o, 16));
    float ex = __expf(v - m);
#pragma unroll
    for (int o = 8; o >= 1; o >>= 1) ex += __shfl_xor(ex, o, 16);
    out[(unsigned int)g * 16u + f] = (v - m) - __logf(ex);
}

extern "C" void kernel_launch(void* const* d_in, const int* in_sizes, int n_in,
                              void* d_out, int out_size, void* d_ws, size_t ws_size,
                              hipStream_t stream) {
    const float* x  = (const float*)d_in[0];
    const void*  ei = d_in[1];
    const float* W1 = (const float*)d_in[2];
    const float* b1 = (const float*)d_in[3];
    const float* W2 = (const float*)d_in[4];
    const float* b2 = (const float*)d_in[5];

    long long dh  = in_sizes[3];                 // 64
    long long din = in_sizes[2] / dh;            // 64
    long long n   = in_sizes[0] / din;           // 50000
    long long E   = (long long)in_sizes[1] / 2;  // 1.6M
    int nbuckets  = (int)((n + BNODES - 1) >> BSHIFT);  // 782

    // slice size: keep block count <= 256 (k_scanB width)
    long long epb = 8192;
    while ((E + epb - 1) / epb > 256) epb <<= 1;
    int nblk = (int)((E + epb - 1) / epb);       // 196 for E=1.6M
    int ngemm = (int)(n / 16);                   // 3125 gemm1 blocks

    char* ws = (char*)d_ws;
    auto alloc = [&](size_t bytes) { void* p = ws; ws += (bytes + 255) & ~255ULL; return p; };
    int*   totals   = (int*)alloc(nbuckets * 4);
    int*   base     = (int*)alloc(nbuckets * 4);
    int*   rowstart = (int*)alloc(n * 4);
    int*   counts   = (int*)alloc(n * 4);
    float* dinv     = (float*)alloc(n * 4);
    int*   partial  = (int*)alloc((size_t)nbuckets * nblk * 4);
    unsigned int* keys = (unsigned int*)alloc(E * 4);
    unsigned short* h1b  = (unsigned short*)alloc(n * 64 * 2);
    unsigned short* h2b  = (unsigned short*)alloc(n * 16 * 2);
    unsigned int* sort_scratch = (unsigned int*)alloc(E * 4);  // big-bucket fallback

    float* out = (float*)d_out;

    // fat launch: hist (blocks 0..nblk) overlapped with gemm1 (rest)
    k_hist_gemm1<<<nblk + ngemm, 256, 0, stream>>>(ei, n, E, epb, nbuckets, nblk,
                                                   partial, x, W1, h1b);
    k_scanB<<<nbuckets, 256, 0, stream>>>(partial, nblk, totals);
    k_scan<<<1, 1024, 0, stream>>>(totals, nbuckets, base);
    k_place<<<nblk, 512, 0, stream>>>(ei, n, E, epb, nbuckets, nblk, base, partial, keys);
    k_sortdeg<<<nbuckets, 256, 0, stream>>>(keys, base, totals, rowstart, counts,
                                            dinv, (int)n, sort_scratch);

    // layer 1 aggregation (+ fused layer-2 GEMM in epilogue)
    k_agg64<<<(int)((n * 64 + 255) / 256), 256, 0, stream>>>(
        rowstart, counts, keys, (const uint2*)h1b, dinv, b1, W2, h2b, (int)n);

    // layer 2 aggregation + log_softmax
    k_agg16<<<(int)((n * 16 + 255) / 256), 256, 0, stream>>>(
        rowstart, counts, keys, h2b, dinv, b2, out, (int)n);
}